// Round 1
// baseline (772.231 us; speedup 1.0000x reference)
//
#include <hip/hip_runtime.h>

#define NN 50000
#define NE 800000
#define NF 64
#define NG 64
#define NC 16

__global__ void deg_kernel(const int* __restrict__ dst, float* __restrict__ deg, int E) {
    int e = blockIdx.x * blockDim.x + threadIdx.x;
    if (e < E) atomicAdd(&deg[dst[e]], 1.0f);
}

__global__ void dinv_kernel(const float* __restrict__ deg, float* __restrict__ dinv, int n) {
    int i = blockIdx.x * blockDim.x + threadIdx.x;
    if (i < n) dinv[i] = rsqrtf(deg[i] + 1.0f);
}

// H[n,64] = X[n,64] @ W[64,64]; one wave per row, lane j = output col j
__global__ void gemm64_kernel(const float* __restrict__ X, const float* __restrict__ W,
                              float* __restrict__ H, int n) {
    __shared__ float sW[64][65];
    __shared__ float sX[4][64];
    for (int i = threadIdx.x; i < 4096; i += 256) sW[i >> 6][i & 63] = W[i];
    int w = threadIdx.x >> 6, j = threadIdx.x & 63;
    int row = blockIdx.x * 4 + w;
    if (row < n) sX[w][j] = X[row * 64 + j];
    __syncthreads();
    if (row < n) {
        float acc = 0.f;
        #pragma unroll
        for (int k = 0; k < 64; ++k) acc = fmaf(sX[w][k], sW[k][j], acc);
        H[row * 64 + j] = acc;
    }
}

// one wave per edge; lane j handles feature j
__global__ void scatter_kernel(const float* __restrict__ H, const int* __restrict__ src,
                               const int* __restrict__ dst, const float* __restrict__ dinv,
                               float* __restrict__ agg, int E) {
    int e = blockIdx.x * 4 + (threadIdx.x >> 6);
    int j = threadIdx.x & 63;
    if (e < E) {
        int s = src[e], d = dst[e];
        float norm = dinv[s] * dinv[d];
        atomicAdd(&agg[d * 64 + j], H[s * 64 + j] * norm);
    }
}

// agg = agg + H*dinv^2 + b, optional relu (in place on agg)
__global__ void epilogue_kernel(float* __restrict__ agg, const float* __restrict__ H,
                                const float* __restrict__ dinv, const float* __restrict__ b,
                                int n, int do_relu) {
    int i = blockIdx.x * blockDim.x + threadIdx.x;
    if (i < n * NF) {
        int node = i >> 6, j = i & 63;
        float di = dinv[node];
        float v = agg[i] + H[i] * di * di + b[j];
        if (do_relu) v = fmaxf(v, 0.f);
        agg[i] = v;
    }
}

// one block per graph; batch is sorted -> binary search the range
__global__ void pool_kernel(const float* __restrict__ H, const int* __restrict__ batch,
                            float* __restrict__ pooled, int n) {
    int g = blockIdx.x;
    int lo = 0, hi = n;
    while (lo < hi) { int m = (lo + hi) >> 1; if (batch[m] < g) lo = m + 1; else hi = m; }
    int start = lo;
    lo = start; hi = n;
    while (lo < hi) { int m = (lo + hi) >> 1; if (batch[m] < g + 1) lo = m + 1; else hi = m; }
    int end = lo;

    int f = threadIdx.x & 63, c = threadIdx.x >> 6;   // 4 node-chunks x 64 feats
    float s = 0.f, m = -INFINITY;
    for (int i = start + c; i < end; i += 4) {
        float v = H[i * NF + f];
        s += v; m = fmaxf(m, v);
    }
    __shared__ float ss[4][64], sm[4][64];
    ss[c][f] = s; sm[c][f] = m;
    __syncthreads();
    if (c == 0) {
        float sum = ss[0][f] + ss[1][f] + ss[2][f] + ss[3][f];
        float mx = fmaxf(fmaxf(sm[0][f], sm[1][f]), fmaxf(sm[2][f], sm[3][f]));
        int cnt = end - start;
        pooled[g * 128 + f] = sum / fmaxf((float)cnt, 1.0f);
        pooled[g * 128 + 64 + f] = mx;
    }
}

__global__ void final_kernel(const float* __restrict__ pooled, const float* __restrict__ Wlin,
                             const float* __restrict__ blin, float* __restrict__ out) {
    int g = blockIdx.x;
    int c = threadIdx.x;   // 16
    float acc = blin[c];
    #pragma unroll 8
    for (int k = 0; k < 128; ++k) acc = fmaf(pooled[g * 128 + k], Wlin[k * NC + c], acc);
    out[g * NC + c] = acc;
}

extern "C" void kernel_launch(void* const* d_in, const int* in_sizes, int n_in,
                              void* d_out, int out_size, void* d_ws, size_t ws_size,
                              hipStream_t stream) {
    const float* x     = (const float*)d_in[0];
    const int*   ei    = (const int*)d_in[1];
    const int*   batch = (const int*)d_in[2];
    const float* W1    = (const float*)d_in[3];
    const float* b1    = (const float*)d_in[4];
    const float* W2    = (const float*)d_in[5];
    const float* b2    = (const float*)d_in[6];
    const float* W3    = (const float*)d_in[7];
    const float* b3    = (const float*)d_in[8];
    const float* Wlin  = (const float*)d_in[9];
    const float* blin  = (const float*)d_in[10];
    const int* src = ei;
    const int* dst = ei + NE;
    float* out = (float*)d_out;

    float* ws     = (float*)d_ws;
    float* dinv   = ws;                 // 50048 floats
    float* bufA   = ws + 50048;         // 3,200,000 floats
    float* bufB   = bufA + NN * NF;     // 3,200,000 floats
    float* pooled = bufB + NN * NF;     // 8192 floats

    // degree (temporarily in bufB) -> dinv
    hipMemsetAsync(bufB, 0, NN * sizeof(float), stream);
    deg_kernel<<<(NE + 255) / 256, 256, 0, stream>>>(dst, bufB, NE);
    dinv_kernel<<<(NN + 255) / 256, 256, 0, stream>>>(bufB, dinv, NN);

    const float* Ws[3] = {W1, W2, W3};
    const float* bs[3] = {b1, b2, b3};
    const float* cur = x;
    for (int l = 0; l < 3; ++l) {
        gemm64_kernel<<<(NN + 3) / 4, 256, 0, stream>>>(cur, Ws[l], bufA, NN);
        hipMemsetAsync(bufB, 0, (size_t)NN * NF * sizeof(float), stream);
        scatter_kernel<<<(NE + 3) / 4, 256, 0, stream>>>(bufA, src, dst, dinv, bufB, NE);
        epilogue_kernel<<<(NN * NF + 255) / 256, 256, 0, stream>>>(bufB, bufA, dinv, bs[l],
                                                                   NN, l < 2 ? 1 : 0);
        cur = bufB;
    }

    pool_kernel<<<NG, 256, 0, stream>>>(bufB, batch, pooled, NN);
    final_kernel<<<NG, 16, 0, stream>>>(pooled, Wlin, blin, out);
}

// Round 2
// 431.995 us; speedup vs baseline: 1.7876x; 1.7876x over previous
//
#include <hip/hip_runtime.h>

#define NN 50000
#define NE 800000
#define NF 64
#define NG 64
#define NC 16

// ---- CSR build ----------------------------------------------------------

__global__ void count_kernel(const int* __restrict__ dst, int* __restrict__ cnt, int E) {
    int e = blockIdx.x * blockDim.x + threadIdx.x;
    if (e < E) atomicAdd(&cnt[dst[e]], 1);
}

__global__ void dinv_kernel(const int* __restrict__ cnt, float* __restrict__ dinv, int n) {
    int i = blockIdx.x * blockDim.x + threadIdx.x;
    if (i < n) dinv[i] = rsqrtf((float)cnt[i] + 1.0f);
}

// single-block exclusive scan of cnt[0..n) -> row_ptr[0..n], row_ptr[n] = total
__global__ void __launch_bounds__(1024) scan_kernel(const int* __restrict__ cnt,
                                                    int* __restrict__ row_ptr, int n) {
    __shared__ int wsum[16];
    __shared__ int carry_s;
    int tid = threadIdx.x;
    int lane = tid & 63, wid = tid >> 6;
    if (tid == 0) carry_s = 0;
    __syncthreads();
    for (int base = 0; base < n; base += 1024) {
        int i = base + tid;
        int v = (i < n) ? cnt[i] : 0;
        int s = v;
        #pragma unroll
        for (int d = 1; d < 64; d <<= 1) {
            int t = __shfl_up(s, d, 64);
            if (lane >= d) s += t;
        }
        if (lane == 63) wsum[wid] = s;
        __syncthreads();
        int woff = 0;
        for (int k = 0; k < wid; ++k) woff += wsum[k];
        int total = 0;
        #pragma unroll
        for (int k = 0; k < 16; ++k) total += wsum[k];
        int excl = carry_s + woff + s - v;
        if (i < n) row_ptr[i] = excl;
        __syncthreads();
        if (tid == 0) carry_s += total;
        __syncthreads();
    }
    if (tid == 0) row_ptr[n] = carry_s;
}

__global__ void cursor_kernel(const int* __restrict__ row_ptr, int* __restrict__ cursor, int n) {
    int i = blockIdx.x * blockDim.x + threadIdx.x;
    if (i < n) cursor[i] = row_ptr[i];
}

__global__ void fill_kernel(const int* __restrict__ src, const int* __restrict__ dst,
                            int* __restrict__ cursor, int* __restrict__ csr_src, int E) {
    int e = blockIdx.x * blockDim.x + threadIdx.x;
    if (e < E) {
        int d = dst[e];
        int pos = atomicAdd(&cursor[d], 1);
        csr_src[pos] = src[e];
    }
}

// ---- layers -------------------------------------------------------------

// Hs[n,64] = (X[n,64] @ W[64,64]) * dinv[row]; one wave per row, lane j = col j
__global__ void gemm64_kernel(const float* __restrict__ X, const float* __restrict__ W,
                              const float* __restrict__ dinv, float* __restrict__ Hs, int n) {
    __shared__ float sW[64][65];
    __shared__ float sX[4][64];
    for (int i = threadIdx.x; i < 4096; i += 256) sW[i >> 6][i & 63] = W[i];
    int w = threadIdx.x >> 6, j = threadIdx.x & 63;
    int row = blockIdx.x * 4 + w;
    if (row < n) sX[w][j] = X[row * 64 + j];
    __syncthreads();
    if (row < n) {
        float acc = 0.f;
        #pragma unroll
        for (int k = 0; k < 64; ++k) acc = fmaf(sX[w][k], sW[k][j], acc);
        Hs[row * 64 + j] = acc * dinv[row];
    }
}

// out[d] = relu?( dinv[d]*(sum_{s in N(d)} Hs[s] + Hs[d]) + b )
// one wave per node, lane j = feature j; 4-deep unroll for MLP
__global__ void agg_kernel(const float* __restrict__ Hs, const int* __restrict__ row_ptr,
                           const int* __restrict__ csr_src, const float* __restrict__ dinv,
                           const float* __restrict__ bias, float* __restrict__ out,
                           int n, int do_relu) {
    int node = blockIdx.x * 4 + (threadIdx.x >> 6);
    int j = threadIdx.x & 63;
    if (node >= n) return;
    int s0 = row_ptr[node], s1 = row_ptr[node + 1];
    float a0 = Hs[node * 64 + j];  // self-loop term
    float a1 = 0.f, a2 = 0.f, a3 = 0.f;
    int k = s0;
    for (; k + 3 < s1; k += 4) {
        int i0 = csr_src[k], i1 = csr_src[k + 1], i2 = csr_src[k + 2], i3 = csr_src[k + 3];
        a0 += Hs[i0 * 64 + j];
        a1 += Hs[i1 * 64 + j];
        a2 += Hs[i2 * 64 + j];
        a3 += Hs[i3 * 64 + j];
    }
    for (; k < s1; ++k) a0 += Hs[csr_src[k] * 64 + j];
    float v = (a0 + a1 + a2 + a3) * dinv[node] + bias[j];
    if (do_relu) v = fmaxf(v, 0.f);
    out[node * 64 + j] = v;
}

// ---- pooling / classifier ------------------------------------------------

__global__ void pool_kernel(const float* __restrict__ H, const int* __restrict__ batch,
                            float* __restrict__ pooled, int n) {
    int g = blockIdx.x;
    int lo = 0, hi = n;
    while (lo < hi) { int m = (lo + hi) >> 1; if (batch[m] < g) lo = m + 1; else hi = m; }
    int start = lo;
    lo = start; hi = n;
    while (lo < hi) { int m = (lo + hi) >> 1; if (batch[m] < g + 1) lo = m + 1; else hi = m; }
    int end = lo;

    int f = threadIdx.x & 63, c = threadIdx.x >> 6;
    float s = 0.f, m = -INFINITY;
    for (int i = start + c; i < end; i += 4) {
        float v = H[i * NF + f];
        s += v; m = fmaxf(m, v);
    }
    __shared__ float ss[4][64], sm[4][64];
    ss[c][f] = s; sm[c][f] = m;
    __syncthreads();
    if (c == 0) {
        float sum = ss[0][f] + ss[1][f] + ss[2][f] + ss[3][f];
        float mx = fmaxf(fmaxf(sm[0][f], sm[1][f]), fmaxf(sm[2][f], sm[3][f]));
        int cnt = end - start;
        pooled[g * 128 + f] = sum / fmaxf((float)cnt, 1.0f);
        pooled[g * 128 + 64 + f] = mx;
    }
}

__global__ void final_kernel(const float* __restrict__ pooled, const float* __restrict__ Wlin,
                             const float* __restrict__ blin, float* __restrict__ out) {
    int g = blockIdx.x;
    int c = threadIdx.x;   // 16
    float acc = blin[c];
    #pragma unroll 8
    for (int k = 0; k < 128; ++k) acc = fmaf(pooled[g * 128 + k], Wlin[k * NC + c], acc);
    out[g * NC + c] = acc;
}

// ---- launch ---------------------------------------------------------------

extern "C" void kernel_launch(void* const* d_in, const int* in_sizes, int n_in,
                              void* d_out, int out_size, void* d_ws, size_t ws_size,
                              hipStream_t stream) {
    const float* x     = (const float*)d_in[0];
    const int*   ei    = (const int*)d_in[1];
    const int*   batch = (const int*)d_in[2];
    const float* W1    = (const float*)d_in[3];
    const float* b1    = (const float*)d_in[4];
    const float* W2    = (const float*)d_in[5];
    const float* b2    = (const float*)d_in[6];
    const float* W3    = (const float*)d_in[7];
    const float* b3    = (const float*)d_in[8];
    const float* Wlin  = (const float*)d_in[9];
    const float* blin  = (const float*)d_in[10];
    const int* src = ei;
    const int* dst = ei + NE;
    float* out = (float*)d_out;

    // workspace layout
    int*   cnt     = (int*)d_ws;               // 50000
    int*   row_ptr = cnt + NN;                 // 50001
    int*   cursor  = row_ptr + NN + 1;         // 50000
    int*   csr_src = cursor + NN;              // 800000
    float* dinv    = (float*)(csr_src + NE);   // 50000
    float* bufA    = dinv + NN;                // 3.2M
    float* bufB    = bufA + (size_t)NN * NF;   // 3.2M
    float* pooled  = bufB + (size_t)NN * NF;   // 8192

    // CSR build + dinv
    hipMemsetAsync(cnt, 0, NN * sizeof(int), stream);
    count_kernel<<<(NE + 255) / 256, 256, 0, stream>>>(dst, cnt, NE);
    dinv_kernel<<<(NN + 255) / 256, 256, 0, stream>>>(cnt, dinv, NN);
    scan_kernel<<<1, 1024, 0, stream>>>(cnt, row_ptr, NN);
    cursor_kernel<<<(NN + 255) / 256, 256, 0, stream>>>(row_ptr, cursor, NN);
    fill_kernel<<<(NE + 255) / 256, 256, 0, stream>>>(src, dst, cursor, csr_src, NE);

    // 3 GCN layers
    const float* Ws[3] = {W1, W2, W3};
    const float* bs[3] = {b1, b2, b3};
    const float* cur = x;
    for (int l = 0; l < 3; ++l) {
        gemm64_kernel<<<(NN + 3) / 4, 256, 0, stream>>>(cur, Ws[l], dinv, bufA, NN);
        agg_kernel<<<(NN + 3) / 4, 256, 0, stream>>>(bufA, row_ptr, csr_src, dinv, bs[l],
                                                     bufB, NN, l < 2 ? 1 : 0);
        cur = bufB;
    }

    pool_kernel<<<NG, 256, 0, stream>>>(bufB, batch, pooled, NN);
    final_kernel<<<NG, 16, 0, stream>>>(pooled, Wlin, blin, out);
}

// Round 3
// 362.451 us; speedup vs baseline: 2.1306x; 1.1919x over previous
//
#include <hip/hip_runtime.h>

#define NN 50000
#define NE 800000
#define NF 64
#define NG 64
#define NC 16
#define NSLICE 16

// ---- CSR build ----------------------------------------------------------

__global__ void count_kernel(const int* __restrict__ dst, int* __restrict__ cnt, int E) {
    int e = blockIdx.x * blockDim.x + threadIdx.x;
    if (e < E) atomicAdd(&cnt[dst[e]], 1);
}

__global__ void dinv_kernel(const int* __restrict__ cnt, float* __restrict__ dinv, int n) {
    int i = blockIdx.x * blockDim.x + threadIdx.x;
    if (i < n) dinv[i] = rsqrtf((float)cnt[i] + 1.0f);
}

// single-block exclusive scan of cnt[0..n) -> row_ptr[0..n], row_ptr[n] = total
__global__ void __launch_bounds__(1024) scan_kernel(const int* __restrict__ cnt,
                                                    int* __restrict__ row_ptr, int n) {
    __shared__ int wsum[16];
    __shared__ int carry_s;
    int tid = threadIdx.x;
    int lane = tid & 63, wid = tid >> 6;
    if (tid == 0) carry_s = 0;
    __syncthreads();
    for (int base = 0; base < n; base += 1024) {
        int i = base + tid;
        int v = (i < n) ? cnt[i] : 0;
        int s = v;
        #pragma unroll
        for (int d = 1; d < 64; d <<= 1) {
            int t = __shfl_up(s, d, 64);
            if (lane >= d) s += t;
        }
        if (lane == 63) wsum[wid] = s;
        __syncthreads();
        int woff = 0;
        for (int k = 0; k < wid; ++k) woff += wsum[k];
        int total = 0;
        #pragma unroll
        for (int k = 0; k < 16; ++k) total += wsum[k];
        int excl = carry_s + woff + s - v;
        if (i < n) row_ptr[i] = excl;
        __syncthreads();
        if (tid == 0) carry_s += total;
        __syncthreads();
    }
    if (tid == 0) row_ptr[n] = carry_s;
}

__global__ void cursor_kernel(const int* __restrict__ row_ptr, int* __restrict__ cursor, int n) {
    int i = blockIdx.x * blockDim.x + threadIdx.x;
    if (i < n) cursor[i] = row_ptr[i];
}

__global__ void fill_kernel(const int* __restrict__ src, const int* __restrict__ dst,
                            int* __restrict__ cursor, int* __restrict__ csr_src, int E) {
    int e = blockIdx.x * blockDim.x + threadIdx.x;
    if (e < E) {
        int d = dst[e];
        int pos = atomicAdd(&cursor[d], 1);
        csr_src[pos] = src[e];
    }
}

// ---- layers -------------------------------------------------------------

// Xs = x * dinv[row]
__global__ void prescale_kernel(const float* __restrict__ x, const float* __restrict__ dinv,
                                float* __restrict__ Xs, int n) {
    int i = blockIdx.x * blockDim.x + threadIdx.x;
    if (i < n * NF) Xs[i] = x[i] * dinv[i >> 6];
}

// Fused GCN layer on pre-scaled input Xs (= h * dinv):
//   agg_d = sum_{s in N(d)} Xs[s] + Xs[d]          (gather, linear in h)
//   v     = dinv[d] * (agg_d @ W) + b
//   out   = relu?(v) * (scale_out ? dinv[d] : 1)
// one wave per node, lane j = feature j; W staged in LDS
__global__ void layer_kernel(const float* __restrict__ Xs, const int* __restrict__ row_ptr,
                             const int* __restrict__ csr_src, const float* __restrict__ dinv,
                             const float* __restrict__ W, const float* __restrict__ bias,
                             float* __restrict__ out, int n, int do_relu, int scale_out) {
    __shared__ float sW[64][65];
    __shared__ float sAgg[4][64];
    for (int i = threadIdx.x; i < 4096; i += 256) sW[i >> 6][i & 63] = W[i];
    int w = threadIdx.x >> 6, j = threadIdx.x & 63;
    int node = blockIdx.x * 4 + w;

    float a0 = 0.f, a1 = 0.f, a2 = 0.f, a3 = 0.f;
    if (node < n) {
        int s0 = row_ptr[node], s1 = row_ptr[node + 1];
        a0 = Xs[node * 64 + j];                     // self-loop term (already dinv-scaled)
        int k = s0;
        for (; k + 3 < s1; k += 4) {
            int i0 = csr_src[k], i1 = csr_src[k + 1], i2 = csr_src[k + 2], i3 = csr_src[k + 3];
            a0 += Xs[i0 * 64 + j];
            a1 += Xs[i1 * 64 + j];
            a2 += Xs[i2 * 64 + j];
            a3 += Xs[i3 * 64 + j];
        }
        for (; k < s1; ++k) a0 += Xs[csr_src[k] * 64 + j];
    }
    sAgg[w][j] = (a0 + a1) + (a2 + a3);
    __syncthreads();
    if (node < n) {
        float acc = 0.f;
        #pragma unroll
        for (int k = 0; k < 64; ++k) acc = fmaf(sAgg[w][k], sW[k][j], acc);
        float di = dinv[node];
        float v = acc * di + bias[j];
        if (do_relu) v = fmaxf(v, 0.f);
        if (scale_out) v *= di;
        out[node * 64 + j] = v;
    }
}

// ---- pooling / classifier ------------------------------------------------

// stage 1: one block per (graph, slice); partial sum/max over the slice
__global__ void pool1_kernel(const float* __restrict__ H, const int* __restrict__ batch,
                             float* __restrict__ partial, int n) {
    int g = blockIdx.x >> 4, sl = blockIdx.x & (NSLICE - 1);
    int lo = 0, hi = n;
    while (lo < hi) { int m = (lo + hi) >> 1; if (batch[m] < g) lo = m + 1; else hi = m; }
    int start = lo;
    lo = start; hi = n;
    while (lo < hi) { int m = (lo + hi) >> 1; if (batch[m] < g + 1) lo = m + 1; else hi = m; }
    int end = lo;
    int len = end - start;
    int ss = start + (int)((long long)len * sl / NSLICE);
    int se = start + (int)((long long)len * (sl + 1) / NSLICE);

    int f = threadIdx.x & 63, c = threadIdx.x >> 6;
    float s = 0.f, m = -INFINITY;
    for (int i = ss + c; i < se; i += 4) {
        float v = H[i * NF + f];
        s += v; m = fmaxf(m, v);
    }
    __shared__ float ssh[4][64], smh[4][64];
    ssh[c][f] = s; smh[c][f] = m;
    __syncthreads();
    if (c == 0) {
        float sum = ssh[0][f] + ssh[1][f] + ssh[2][f] + ssh[3][f];
        float mx = fmaxf(fmaxf(smh[0][f], smh[1][f]), fmaxf(smh[2][f], smh[3][f]));
        partial[(size_t)blockIdx.x * 128 + f] = sum;
        partial[(size_t)blockIdx.x * 128 + 64 + f] = mx;
    }
}

// stage 2: one block per graph; reduce 16 slices, then fused final linear
__global__ void pool2_kernel(const float* __restrict__ partial, const int* __restrict__ batch,
                             const float* __restrict__ Wlin, const float* __restrict__ blin,
                             float* __restrict__ out, int n) {
    int g = blockIdx.x;
    int t = threadIdx.x;  // 128
    __shared__ float pooled[128];
    if (t < 64) {
        float sum = 0.f;
        for (int sl = 0; sl < NSLICE; ++sl) sum += partial[((size_t)g * NSLICE + sl) * 128 + t];
        int lo = 0, hi = n;
        while (lo < hi) { int m = (lo + hi) >> 1; if (batch[m] < g) lo = m + 1; else hi = m; }
        int start = lo;
        lo = start; hi = n;
        while (lo < hi) { int m = (lo + hi) >> 1; if (batch[m] < g + 1) lo = m + 1; else hi = m; }
        int cnt = lo - start;
        pooled[t] = sum / fmaxf((float)cnt, 1.0f);
    } else {
        int f = t - 64;
        float mx = -INFINITY;
        for (int sl = 0; sl < NSLICE; ++sl)
            mx = fmaxf(mx, partial[((size_t)g * NSLICE + sl) * 128 + 64 + f]);
        pooled[t] = mx;
    }
    __syncthreads();
    if (t < NC) {
        float acc = blin[t];
        #pragma unroll 8
        for (int k = 0; k < 128; ++k) acc = fmaf(pooled[k], Wlin[k * NC + t], acc);
        out[g * NC + t] = acc;
    }
}

// ---- launch ---------------------------------------------------------------

extern "C" void kernel_launch(void* const* d_in, const int* in_sizes, int n_in,
                              void* d_out, int out_size, void* d_ws, size_t ws_size,
                              hipStream_t stream) {
    const float* x     = (const float*)d_in[0];
    const int*   ei    = (const int*)d_in[1];
    const int*   batch = (const int*)d_in[2];
    const float* W1    = (const float*)d_in[3];
    const float* b1    = (const float*)d_in[4];
    const float* W2    = (const float*)d_in[5];
    const float* b2    = (const float*)d_in[6];
    const float* W3    = (const float*)d_in[7];
    const float* b3    = (const float*)d_in[8];
    const float* Wlin  = (const float*)d_in[9];
    const float* blin  = (const float*)d_in[10];
    const int* src = ei;
    const int* dst = ei + NE;
    float* out = (float*)d_out;

    // workspace layout
    int*   cnt     = (int*)d_ws;               // 50000
    int*   row_ptr = cnt + NN;                 // 50001
    int*   cursor  = row_ptr + NN + 1;         // 50000
    int*   csr_src = cursor + NN;              // 800000
    float* dinv    = (float*)(csr_src + NE);   // 50000
    float* bufA    = dinv + NN;                // 3.2M
    float* bufB    = bufA + (size_t)NN * NF;   // 3.2M
    float* partial = bufB + (size_t)NN * NF;   // 64*16*128 = 131072

    // CSR build + dinv
    hipMemsetAsync(cnt, 0, NN * sizeof(int), stream);
    count_kernel<<<(NE + 255) / 256, 256, 0, stream>>>(dst, cnt, NE);
    dinv_kernel<<<(NN + 255) / 256, 256, 0, stream>>>(cnt, dinv, NN);
    scan_kernel<<<1, 1024, 0, stream>>>(cnt, row_ptr, NN);
    cursor_kernel<<<(NN + 255) / 256, 256, 0, stream>>>(row_ptr, cursor, NN);
    fill_kernel<<<(NE + 255) / 256, 256, 0, stream>>>(src, dst, cursor, csr_src, NE);

    // prescale input once: bufA = x * dinv
    prescale_kernel<<<(NN * NF + 255) / 256, 256, 0, stream>>>(x, dinv, bufA, NN);

    // 3 fused GCN layers (input pre-scaled; layers 1,2 emit scaled output)
    layer_kernel<<<(NN + 3) / 4, 256, 0, stream>>>(bufA, row_ptr, csr_src, dinv, W1, b1,
                                                   bufB, NN, 1, 1);
    layer_kernel<<<(NN + 3) / 4, 256, 0, stream>>>(bufB, row_ptr, csr_src, dinv, W2, b2,
                                                   bufA, NN, 1, 1);
    layer_kernel<<<(NN + 3) / 4, 256, 0, stream>>>(bufA, row_ptr, csr_src, dinv, W3, b3,
                                                   bufB, NN, 0, 0);

    // two-stage pool + fused classifier
    pool1_kernel<<<NG * NSLICE, 256, 0, stream>>>(bufB, batch, partial, NN);
    pool2_kernel<<<NG, 128, 0, stream>>>(partial, batch, Wlin, blin, out, NN);
}

// Round 4
// 297.366 us; speedup vs baseline: 2.5969x; 1.2189x over previous
//
#include <hip/hip_runtime.h>

#define NN 50000
#define NE 800000
#define NF 64
#define NG 64
#define NC 16
#define NSLICE 16
#define NB 196  // ceil(NN/256)

// ---- CSR build ----------------------------------------------------------

__global__ void count_kernel(const int* __restrict__ dst, int* __restrict__ cnt, int E) {
    int e = blockIdx.x * blockDim.x + threadIdx.x;
    if (e < E) atomicAdd(&cnt[dst[e]], 1);
}

// pass 1: per-block exclusive scan (256 elems/block) -> row_ptr, block totals
__global__ void scan1_kernel(const int* __restrict__ cnt, int* __restrict__ row_ptr,
                             int* __restrict__ block_sums, int n) {
    int tid = threadIdx.x, lane = tid & 63, wid = tid >> 6;
    int i = blockIdx.x * 256 + tid;
    int v = (i < n) ? cnt[i] : 0;
    int s = v;
    #pragma unroll
    for (int d = 1; d < 64; d <<= 1) {
        int t = __shfl_up(s, d, 64);
        if (lane >= d) s += t;
    }
    __shared__ int ws[4];
    if (lane == 63) ws[wid] = s;
    __syncthreads();
    int woff = 0;
    for (int k = 0; k < wid; ++k) woff += ws[k];
    if (i < n) row_ptr[i] = woff + s - v;
    if (tid == 0) block_sums[blockIdx.x] = ws[0] + ws[1] + ws[2] + ws[3];
}

// pass 2: single block scans the NB block sums in place; total -> block_sums[NB]
__global__ void scan2_kernel(int* __restrict__ block_sums, int nb) {
    int tid = threadIdx.x, lane = tid & 63, wid = tid >> 6;
    int v = (tid < nb) ? block_sums[tid] : 0;
    int s = v;
    #pragma unroll
    for (int d = 1; d < 64; d <<= 1) {
        int t = __shfl_up(s, d, 64);
        if (lane >= d) s += t;
    }
    __shared__ int ws[4];
    if (lane == 63) ws[wid] = s;
    __syncthreads();
    int woff = 0;
    for (int k = 0; k < wid; ++k) woff += ws[k];
    if (tid < nb) block_sums[tid] = woff + s - v;
    if (tid == 0) block_sums[nb] = ws[0] + ws[1] + ws[2] + ws[3];
}

// pass 3: add block offsets; also emit cursor, dinv, row_ptr[n]
__global__ void scan3_kernel(const int* __restrict__ cnt, int* __restrict__ row_ptr,
                             int* __restrict__ cursor, float* __restrict__ dinv,
                             const int* __restrict__ block_sums, int n) {
    int i = blockIdx.x * 256 + threadIdx.x;
    if (i < n) {
        int r = row_ptr[i] + block_sums[blockIdx.x];
        row_ptr[i] = r;
        cursor[i] = r;
        dinv[i] = rsqrtf((float)cnt[i] + 1.0f);
    }
    if (i == 0) row_ptr[n] = block_sums[NB];
}

__global__ void fill_kernel(const int* __restrict__ src, const int* __restrict__ dst,
                            int* __restrict__ cursor, int* __restrict__ csr_src, int E) {
    int e = blockIdx.x * blockDim.x + threadIdx.x;
    if (e < E) {
        int d = dst[e];
        int pos = atomicAdd(&cursor[d], 1);
        csr_src[pos] = src[e];
    }
}

// ---- layers -------------------------------------------------------------

// Xs = x * dinv[row]
__global__ void prescale_kernel(const float* __restrict__ x, const float* __restrict__ dinv,
                                float* __restrict__ Xs, int n) {
    int i = blockIdx.x * blockDim.x + threadIdx.x;
    if (i < n * NF) Xs[i] = x[i] * dinv[i >> 6];
}

// Fused GCN layer on pre-scaled input Xs (= h * dinv):
//   agg_d = sum_{s in N(d)} Xs[s] + Xs[d]; v = dinv[d]*(agg_d @ W) + b
//   out = relu?(v) * (scale_out ? dinv[d] : 1)
// one wave per node; 4 edge-groups x 16 lanes x float4
__global__ void __launch_bounds__(256) layer_kernel(
        const float* __restrict__ Xs, const int* __restrict__ row_ptr,
        const int* __restrict__ csr_src, const float* __restrict__ dinv,
        const float* __restrict__ W, const float* __restrict__ bias,
        float* __restrict__ out, int n, int do_relu, int scale_out) {
    __shared__ float sW[64][65];
    __shared__ float sAgg[4][64];
    for (int i = threadIdx.x; i < 4096; i += 256) sW[i >> 6][i & 63] = W[i];
    int w = threadIdx.x >> 6, lane = threadIdx.x & 63;
    int grp = lane >> 4, sub = lane & 15;
    int node = blockIdx.x * 4 + w;
    const float4* X4 = (const float4*)Xs;

    float4 acc = make_float4(0.f, 0.f, 0.f, 0.f);
    if (node < n) {
        int s0 = row_ptr[node], s1 = row_ptr[node + 1];
        int k = s0 + grp;
        for (; k + 4 < s1; k += 8) {
            int ia = csr_src[k], ib = csr_src[k + 4];
            float4 va = X4[ia * 16 + sub];
            float4 vb = X4[ib * 16 + sub];
            acc.x += va.x + vb.x; acc.y += va.y + vb.y;
            acc.z += va.z + vb.z; acc.w += va.w + vb.w;
        }
        if (k < s1) {
            float4 v = X4[csr_src[k] * 16 + sub];
            acc.x += v.x; acc.y += v.y; acc.z += v.z; acc.w += v.w;
        }
        if (grp == 0) {  // self-loop term (already dinv-scaled)
            float4 v = X4[node * 16 + sub];
            acc.x += v.x; acc.y += v.y; acc.z += v.z; acc.w += v.w;
        }
    }
    // reduce the 4 edge-groups (lanes differing in bits 4 and 5)
    acc.x += __shfl_xor(acc.x, 16, 64); acc.y += __shfl_xor(acc.y, 16, 64);
    acc.z += __shfl_xor(acc.z, 16, 64); acc.w += __shfl_xor(acc.w, 16, 64);
    acc.x += __shfl_xor(acc.x, 32, 64); acc.y += __shfl_xor(acc.y, 32, 64);
    acc.z += __shfl_xor(acc.z, 32, 64); acc.w += __shfl_xor(acc.w, 32, 64);
    if (lane < 16) *((float4*)&sAgg[w][lane * 4]) = acc;
    __syncthreads();
    if (node < n) {
        float a = 0.f;
        #pragma unroll
        for (int k = 0; k < 64; ++k) a = fmaf(sAgg[w][k], sW[k][lane], a);
        float di = dinv[node];
        float v = a * di + bias[lane];
        if (do_relu) v = fmaxf(v, 0.f);
        if (scale_out) v *= di;
        out[node * 64 + lane] = v;
    }
}

// ---- pooling / classifier ------------------------------------------------

__global__ void pool1_kernel(const float* __restrict__ H, const int* __restrict__ batch,
                             float* __restrict__ partial, int n) {
    int g = blockIdx.x >> 4, sl = blockIdx.x & (NSLICE - 1);
    int lo = 0, hi = n;
    while (lo < hi) { int m = (lo + hi) >> 1; if (batch[m] < g) lo = m + 1; else hi = m; }
    int start = lo;
    lo = start; hi = n;
    while (lo < hi) { int m = (lo + hi) >> 1; if (batch[m] < g + 1) lo = m + 1; else hi = m; }
    int end = lo;
    int len = end - start;
    int ss = start + (int)((long long)len * sl / NSLICE);
    int se = start + (int)((long long)len * (sl + 1) / NSLICE);

    int f = threadIdx.x & 63, c = threadIdx.x >> 6;
    float s = 0.f, m = -INFINITY;
    for (int i = ss + c; i < se; i += 4) {
        float v = H[i * NF + f];
        s += v; m = fmaxf(m, v);
    }
    __shared__ float ssh[4][64], smh[4][64];
    ssh[c][f] = s; smh[c][f] = m;
    __syncthreads();
    if (c == 0) {
        float sum = ssh[0][f] + ssh[1][f] + ssh[2][f] + ssh[3][f];
        float mx = fmaxf(fmaxf(smh[0][f], smh[1][f]), fmaxf(smh[2][f], smh[3][f]));
        partial[(size_t)blockIdx.x * 128 + f] = sum;
        partial[(size_t)blockIdx.x * 128 + 64 + f] = mx;
    }
}

__global__ void pool2_kernel(const float* __restrict__ partial, const int* __restrict__ batch,
                             const float* __restrict__ Wlin, const float* __restrict__ blin,
                             float* __restrict__ out, int n) {
    int g = blockIdx.x;
    int t = threadIdx.x;  // 128
    __shared__ float pooled[128];
    if (t < 64) {
        float sum = 0.f;
        for (int sl = 0; sl < NSLICE; ++sl) sum += partial[((size_t)g * NSLICE + sl) * 128 + t];
        int lo = 0, hi = n;
        while (lo < hi) { int m = (lo + hi) >> 1; if (batch[m] < g) lo = m + 1; else hi = m; }
        int start = lo;
        lo = start; hi = n;
        while (lo < hi) { int m = (lo + hi) >> 1; if (batch[m] < g + 1) lo = m + 1; else hi = m; }
        int cnt = lo - start;
        pooled[t] = sum / fmaxf((float)cnt, 1.0f);
    } else {
        int f = t - 64;
        float mx = -INFINITY;
        for (int sl = 0; sl < NSLICE; ++sl)
            mx = fmaxf(mx, partial[((size_t)g * NSLICE + sl) * 128 + 64 + f]);
        pooled[t] = mx;
    }
    __syncthreads();
    if (t < NC) {
        float acc = blin[t];
        #pragma unroll 8
        for (int k = 0; k < 128; ++k) acc = fmaf(pooled[k], Wlin[k * NC + t], acc);
        out[g * NC + t] = acc;
    }
}

// ---- launch ---------------------------------------------------------------

extern "C" void kernel_launch(void* const* d_in, const int* in_sizes, int n_in,
                              void* d_out, int out_size, void* d_ws, size_t ws_size,
                              hipStream_t stream) {
    const float* x     = (const float*)d_in[0];
    const int*   ei    = (const int*)d_in[1];
    const int*   batch = (const int*)d_in[2];
    const float* W1    = (const float*)d_in[3];
    const float* b1    = (const float*)d_in[4];
    const float* W2    = (const float*)d_in[5];
    const float* b2    = (const float*)d_in[6];
    const float* W3    = (const float*)d_in[7];
    const float* b3    = (const float*)d_in[8];
    const float* Wlin  = (const float*)d_in[9];
    const float* blin  = (const float*)d_in[10];
    const int* src = ei;
    const int* dst = ei + NE;
    float* out = (float*)d_out;

    // workspace layout
    int*   cnt        = (int*)d_ws;                 // 50000
    int*   row_ptr    = cnt + NN;                   // 50001
    int*   cursor     = row_ptr + NN + 1;           // 50000
    int*   block_sums = cursor + NN;                // 197
    int*   csr_src    = block_sums + NB + 1;        // 800000
    float* dinv       = (float*)(csr_src + NE);     // 50000
    float* bufA       = dinv + NN;                  // 3.2M
    float* bufB       = bufA + (size_t)NN * NF;     // 3.2M
    float* partial    = bufB + (size_t)NN * NF;     // 131072

    // CSR build + dinv
    hipMemsetAsync(cnt, 0, NN * sizeof(int), stream);
    count_kernel<<<(NE + 255) / 256, 256, 0, stream>>>(dst, cnt, NE);
    scan1_kernel<<<NB, 256, 0, stream>>>(cnt, row_ptr, block_sums, NN);
    scan2_kernel<<<1, 256, 0, stream>>>(block_sums, NB);
    scan3_kernel<<<NB, 256, 0, stream>>>(cnt, row_ptr, cursor, dinv, block_sums, NN);
    fill_kernel<<<(NE + 255) / 256, 256, 0, stream>>>(src, dst, cursor, csr_src, NE);

    // prescale input once: bufA = x * dinv
    prescale_kernel<<<(NN * NF + 255) / 256, 256, 0, stream>>>(x, dinv, bufA, NN);

    // 3 fused GCN layers
    layer_kernel<<<(NN + 3) / 4, 256, 0, stream>>>(bufA, row_ptr, csr_src, dinv, W1, b1,
                                                   bufB, NN, 1, 1);
    layer_kernel<<<(NN + 3) / 4, 256, 0, stream>>>(bufB, row_ptr, csr_src, dinv, W2, b2,
                                                   bufA, NN, 1, 1);
    layer_kernel<<<(NN + 3) / 4, 256, 0, stream>>>(bufA, row_ptr, csr_src, dinv, W3, b3,
                                                   bufB, NN, 0, 0);

    // two-stage pool + fused classifier
    pool1_kernel<<<NG * NSLICE, 256, 0, stream>>>(bufB, batch, partial, NN);
    pool2_kernel<<<NG, 128, 0, stream>>>(partial, batch, Wlin, blin, out, NN);
}

// Round 5
// 261.312 us; speedup vs baseline: 2.9552x; 1.1380x over previous
//
#include <hip/hip_runtime.h>

#define NN 50000
#define NE 800000
#define NF 64
#define NG 64
#define NC 16
#define NSLICE 16
#define NB 196  // ceil(NN/256)

// ---- CSR build ----------------------------------------------------------

__global__ void count_kernel(const int* __restrict__ dst, int* __restrict__ cnt, int E) {
    int e = blockIdx.x * blockDim.x + threadIdx.x;
    if (e < E) atomicAdd(&cnt[dst[e]], 1);
}

// pass 1: per-block exclusive scan (256 elems/block) -> row_ptr, block totals
__global__ void scan1_kernel(const int* __restrict__ cnt, int* __restrict__ row_ptr,
                             int* __restrict__ block_sums, int n) {
    int tid = threadIdx.x, lane = tid & 63, wid = tid >> 6;
    int i = blockIdx.x * 256 + tid;
    int v = (i < n) ? cnt[i] : 0;
    int s = v;
    #pragma unroll
    for (int d = 1; d < 64; d <<= 1) {
        int t = __shfl_up(s, d, 64);
        if (lane >= d) s += t;
    }
    __shared__ int ws[4];
    if (lane == 63) ws[wid] = s;
    __syncthreads();
    int woff = 0;
    for (int k = 0; k < wid; ++k) woff += ws[k];
    if (i < n) row_ptr[i] = woff + s - v;
    if (tid == 0) block_sums[blockIdx.x] = ws[0] + ws[1] + ws[2] + ws[3];
}

// pass 2 (fused): each block computes its own prefix over block_sums, then
// finalizes row_ptr, cursor, dinv, and the dinv-prescaled input Xs.
__global__ void scan3_kernel(const int* __restrict__ cnt, int* __restrict__ row_ptr,
                             int* __restrict__ cursor, float* __restrict__ dinv,
                             const int* __restrict__ block_sums,
                             const float* __restrict__ x, float* __restrict__ Xs, int n) {
    int tid = threadIdx.x, lane = tid & 63;
    int bid = blockIdx.x;
    __shared__ int soff_s;
    __shared__ float sDinv[256];
    if (tid < 64) {
        int sum = 0;
        for (int i = lane; i < bid; i += 64) sum += block_sums[i];
        #pragma unroll
        for (int d = 1; d < 64; d <<= 1) sum += __shfl_xor(sum, d, 64);
        if (lane == 0) soff_s = sum;
    }
    __syncthreads();
    int soff = soff_s;
    int i = bid * 256 + tid;
    float dv = 0.f;
    if (i < n) {
        int r = row_ptr[i] + soff;
        row_ptr[i] = r;
        cursor[i] = r;
        dv = rsqrtf((float)cnt[i] + 1.0f);
        dinv[i] = dv;
    }
    sDinv[tid] = dv;
    if (bid == NB - 1 && tid == 0) row_ptr[n] = soff + block_sums[bid];
    __syncthreads();
    // prescale rows [bid*256, bid*256+256): Xs = x * dinv[row]
    const float4* x4 = (const float4*)x;
    float4* Xs4 = (float4*)Xs;
    for (int t = tid; t < 4096; t += 256) {
        int e4 = bid * 4096 + t;          // global float4 index (16 per row)
        int row = e4 >> 4;
        if (row < n) {
            float4 vv = x4[e4];
            float d = sDinv[row - bid * 256];
            vv.x *= d; vv.y *= d; vv.z *= d; vv.w *= d;
            Xs4[e4] = vv;
        }
    }
}

__global__ void fill_kernel(const int* __restrict__ src, const int* __restrict__ dst,
                            int* __restrict__ cursor, int* __restrict__ csr_src, int E) {
    int e = blockIdx.x * blockDim.x + threadIdx.x;
    if (e < E) {
        int d = dst[e];
        int pos = atomicAdd(&cursor[d], 1);
        csr_src[pos] = src[e];
    }
}

// ---- fused GCN layer -----------------------------------------------------
// Input Xs is pre-scaled (= h * dinv). Per node d:
//   agg = sum_{s in N(d)} Xs[s] + Xs[d]
//   v   = dinv[d] * (agg @ W) + b;  out = relu?(v) * (scale_out ? dinv[d] : 1)
// One wave per node. Gather: indices prefetched (1 coalesced load / 64 edges),
// 4 groups x 16 lanes x float4, 4 predicated edges per group per iteration
// (16 independent row loads in flight). Matvec: W transposed in LDS, read as
// float4; agg broadcast via v_readlane (no LDS).
__global__ void __launch_bounds__(256) layer_kernel(
        const float* __restrict__ Xs, const int* __restrict__ row_ptr,
        const int* __restrict__ csr_src, const float* __restrict__ dinv,
        const float* __restrict__ W, const float* __restrict__ bias,
        float* __restrict__ out, int n, int do_relu, int scale_out) {
    __shared__ __align__(16) float sWt[64][68];   // sWt[j][k] = W[k][j], padded
    for (int i = threadIdx.x; i < 4096; i += 256) sWt[i & 63][i >> 6] = W[i];

    int wv_ = threadIdx.x >> 6, lane = threadIdx.x & 63;
    int grp = lane >> 4, sub = lane & 15;
    int node = blockIdx.x * 4 + wv_;
    const float4* X4 = (const float4*)Xs;

    float4 acc = make_float4(0.f, 0.f, 0.f, 0.f);
    if (node < n) {
        int s0 = row_ptr[node], s1 = row_ptr[node + 1];
        for (int base = s0; base < s1; base += 64) {
            int m = s1 - base; if (m > 64) m = 64;
            int ld = (lane < m) ? lane : (m - 1);
            int idx = csr_src[base + ld];
            for (int e0 = grp; e0 < m; e0 += 16) {
                int e1 = e0 + 4, e2 = e0 + 8, e3 = e0 + 12;
                int i0 = __shfl(idx, e0, 64);
                int i1 = __shfl(idx, (e1 < m) ? e1 : e0, 64);
                int i2 = __shfl(idx, (e2 < m) ? e2 : e0, 64);
                int i3 = __shfl(idx, (e3 < m) ? e3 : e0, 64);
                float w1 = (e1 < m) ? 1.f : 0.f;
                float w2 = (e2 < m) ? 1.f : 0.f;
                float w3 = (e3 < m) ? 1.f : 0.f;
                float4 v0 = X4[(size_t)i0 * 16 + sub];
                float4 v1 = X4[(size_t)i1 * 16 + sub];
                float4 v2 = X4[(size_t)i2 * 16 + sub];
                float4 v3 = X4[(size_t)i3 * 16 + sub];
                acc.x += v0.x; acc.y += v0.y; acc.z += v0.z; acc.w += v0.w;
                acc.x = fmaf(w1, v1.x, acc.x); acc.y = fmaf(w1, v1.y, acc.y);
                acc.z = fmaf(w1, v1.z, acc.z); acc.w = fmaf(w1, v1.w, acc.w);
                acc.x = fmaf(w2, v2.x, acc.x); acc.y = fmaf(w2, v2.y, acc.y);
                acc.z = fmaf(w2, v2.z, acc.z); acc.w = fmaf(w2, v2.w, acc.w);
                acc.x = fmaf(w3, v3.x, acc.x); acc.y = fmaf(w3, v3.y, acc.y);
                acc.z = fmaf(w3, v3.z, acc.z); acc.w = fmaf(w3, v3.w, acc.w);
            }
        }
    }
    __syncthreads();   // sWt ready; all threads reach this

    // reduce the 4 edge-groups (every lane ends with agg[4*sub .. 4*sub+3])
    acc.x += __shfl_xor(acc.x, 16, 64); acc.y += __shfl_xor(acc.y, 16, 64);
    acc.z += __shfl_xor(acc.z, 16, 64); acc.w += __shfl_xor(acc.w, 16, 64);
    acc.x += __shfl_xor(acc.x, 32, 64); acc.y += __shfl_xor(acc.y, 32, 64);
    acc.z += __shfl_xor(acc.z, 32, 64); acc.w += __shfl_xor(acc.w, 32, 64);

    if (node >= n) return;

    // self-loop term (already dinv-scaled)
    float4 sv = X4[(size_t)node * 16 + sub];
    acc.x += sv.x; acc.y += sv.y; acc.z += sv.z; acc.w += sv.w;

    // matvec: out_j = sum_c sum_{r<4} agg[4c+r] * W[4c+r][j]
    float o = 0.f;
    #pragma unroll
    for (int c = 0; c < 16; ++c) {
        float4 wvv = *(const float4*)&sWt[lane][c * 4];
        float a0 = __int_as_float(__builtin_amdgcn_readlane(__float_as_int(acc.x), c));
        float a1 = __int_as_float(__builtin_amdgcn_readlane(__float_as_int(acc.y), c));
        float a2 = __int_as_float(__builtin_amdgcn_readlane(__float_as_int(acc.z), c));
        float a3 = __int_as_float(__builtin_amdgcn_readlane(__float_as_int(acc.w), c));
        o = fmaf(a0, wvv.x, o); o = fmaf(a1, wvv.y, o);
        o = fmaf(a2, wvv.z, o); o = fmaf(a3, wvv.w, o);
    }
    float di = dinv[node];
    float v = o * di + bias[lane];
    if (do_relu) v = fmaxf(v, 0.f);
    if (scale_out) v *= di;
    out[(size_t)node * 64 + lane] = v;
}

// ---- pooling / classifier ------------------------------------------------

__global__ void pool1_kernel(const float* __restrict__ H, const int* __restrict__ batch,
                             float* __restrict__ partial, int n) {
    int g = blockIdx.x >> 4, sl = blockIdx.x & (NSLICE - 1);
    int lo = 0, hi = n;
    while (lo < hi) { int m = (lo + hi) >> 1; if (batch[m] < g) lo = m + 1; else hi = m; }
    int start = lo;
    lo = start; hi = n;
    while (lo < hi) { int m = (lo + hi) >> 1; if (batch[m] < g + 1) lo = m + 1; else hi = m; }
    int end = lo;
    int len = end - start;
    int ss = start + (int)((long long)len * sl / NSLICE);
    int se = start + (int)((long long)len * (sl + 1) / NSLICE);

    int f = threadIdx.x & 63, c = threadIdx.x >> 6;
    float s = 0.f, m = -INFINITY;
    for (int i = ss + c; i < se; i += 4) {
        float v = H[i * NF + f];
        s += v; m = fmaxf(m, v);
    }
    __shared__ float ssh[4][64], smh[4][64];
    ssh[c][f] = s; smh[c][f] = m;
    __syncthreads();
    if (c == 0) {
        float sum = ssh[0][f] + ssh[1][f] + ssh[2][f] + ssh[3][f];
        float mx = fmaxf(fmaxf(smh[0][f], smh[1][f]), fmaxf(smh[2][f], smh[3][f]));
        partial[(size_t)blockIdx.x * 128 + f] = sum;
        partial[(size_t)blockIdx.x * 128 + 64 + f] = mx;
    }
}

__global__ void pool2_kernel(const float* __restrict__ partial, const int* __restrict__ batch,
                             const float* __restrict__ Wlin, const float* __restrict__ blin,
                             float* __restrict__ out, int n) {
    int g = blockIdx.x;
    int t = threadIdx.x;  // 128
    __shared__ float pooled[128];
    if (t < 64) {
        float sum = 0.f;
        for (int sl = 0; sl < NSLICE; ++sl) sum += partial[((size_t)g * NSLICE + sl) * 128 + t];
        int lo = 0, hi = n;
        while (lo < hi) { int m = (lo + hi) >> 1; if (batch[m] < g) lo = m + 1; else hi = m; }
        int start = lo;
        lo = start; hi = n;
        while (lo < hi) { int m = (lo + hi) >> 1; if (batch[m] < g + 1) lo = m + 1; else hi = m; }
        int cnt = lo - start;
        pooled[t] = sum / fmaxf((float)cnt, 1.0f);
    } else {
        int f = t - 64;
        float mx = -INFINITY;
        for (int sl = 0; sl < NSLICE; ++sl)
            mx = fmaxf(mx, partial[((size_t)g * NSLICE + sl) * 128 + 64 + f]);
        pooled[t] = mx;
    }
    __syncthreads();
    if (t < NC) {
        float acc = blin[t];
        #pragma unroll 8
        for (int k = 0; k < 128; ++k) acc = fmaf(pooled[k], Wlin[k * NC + t], acc);
        out[g * NC + t] = acc;
    }
}

// ---- launch ---------------------------------------------------------------

extern "C" void kernel_launch(void* const* d_in, const int* in_sizes, int n_in,
                              void* d_out, int out_size, void* d_ws, size_t ws_size,
                              hipStream_t stream) {
    const float* x     = (const float*)d_in[0];
    const int*   ei    = (const int*)d_in[1];
    const int*   batch = (const int*)d_in[2];
    const float* W1    = (const float*)d_in[3];
    const float* b1    = (const float*)d_in[4];
    const float* W2    = (const float*)d_in[5];
    const float* b2    = (const float*)d_in[6];
    const float* W3    = (const float*)d_in[7];
    const float* b3    = (const float*)d_in[8];
    const float* Wlin  = (const float*)d_in[9];
    const float* blin  = (const float*)d_in[10];
    const int* src = ei;
    const int* dst = ei + NE;
    float* out = (float*)d_out;

    // workspace layout
    int*   cnt        = (int*)d_ws;                 // 50000
    int*   row_ptr    = cnt + NN;                   // 50001
    int*   cursor     = row_ptr + NN + 1;           // 50000
    int*   block_sums = cursor + NN;                // 197 (pad to 256)
    int*   csr_src    = block_sums + 256;           // 800000
    float* dinv       = (float*)(csr_src + NE);     // 50000
    float* bufA       = dinv + NN;                  // 3.2M  (16B-aligned: offsets all x4)
    float* bufB       = bufA + (size_t)NN * NF;     // 3.2M
    float* partial    = bufB + (size_t)NN * NF;     // 131072

    // CSR build + dinv + prescale
    hipMemsetAsync(cnt, 0, NN * sizeof(int), stream);
    count_kernel<<<(NE + 255) / 256, 256, 0, stream>>>(dst, cnt, NE);
    scan1_kernel<<<NB, 256, 0, stream>>>(cnt, row_ptr, block_sums, NN);
    scan3_kernel<<<NB, 256, 0, stream>>>(cnt, row_ptr, cursor, dinv, block_sums, x, bufA, NN);
    fill_kernel<<<(NE + 255) / 256, 256, 0, stream>>>(src, dst, cursor, csr_src, NE);

    // 3 fused GCN layers
    layer_kernel<<<(NN + 3) / 4, 256, 0, stream>>>(bufA, row_ptr, csr_src, dinv, W1, b1,
                                                   bufB, NN, 1, 1);
    layer_kernel<<<(NN + 3) / 4, 256, 0, stream>>>(bufB, row_ptr, csr_src, dinv, W2, b2,
                                                   bufA, NN, 1, 1);
    layer_kernel<<<(NN + 3) / 4, 256, 0, stream>>>(bufA, row_ptr, csr_src, dinv, W3, b3,
                                                   bufB, NN, 0, 0);

    // two-stage pool + fused classifier
    pool1_kernel<<<NG * NSLICE, 256, 0, stream>>>(bufB, batch, partial, NN);
    pool2_kernel<<<NG, 128, 0, stream>>>(partial, batch, Wlin, blin, out, NN);
}

// Round 6
// 236.251 us; speedup vs baseline: 3.2687x; 1.1061x over previous
//
#include <hip/hip_runtime.h>

#define NN 50000
#define NE 800000
#define NF 64
#define NG 64
#define NC 16
#define NSLICE 16
#define NB 196  // ceil(NN/256)

// ---- CSR build ----------------------------------------------------------

// 4 edges per thread via int4
__global__ void count_kernel(const int* __restrict__ dst, int* __restrict__ cnt, int E) {
    int t = blockIdx.x * blockDim.x + threadIdx.x;
    int e = t * 4;
    if (e + 3 < E) {
        int4 d = *(const int4*)&dst[e];
        atomicAdd(&cnt[d.x], 1); atomicAdd(&cnt[d.y], 1);
        atomicAdd(&cnt[d.z], 1); atomicAdd(&cnt[d.w], 1);
    } else {
        for (int k = e; k < E; ++k) atomicAdd(&cnt[dst[k]], 1);
    }
}

// pass 1: per-block exclusive scan (256 elems/block) -> row_ptr, block totals
__global__ void scan1_kernel(const int* __restrict__ cnt, int* __restrict__ row_ptr,
                             int* __restrict__ block_sums, int n) {
    int tid = threadIdx.x, lane = tid & 63, wid = tid >> 6;
    int i = blockIdx.x * 256 + tid;
    int v = (i < n) ? cnt[i] : 0;
    int s = v;
    #pragma unroll
    for (int d = 1; d < 64; d <<= 1) {
        int t = __shfl_up(s, d, 64);
        if (lane >= d) s += t;
    }
    __shared__ int ws[4];
    if (lane == 63) ws[wid] = s;
    __syncthreads();
    int woff = 0;
    for (int k = 0; k < wid; ++k) woff += ws[k];
    if (i < n) row_ptr[i] = woff + s - v;
    if (tid == 0) block_sums[blockIdx.x] = ws[0] + ws[1] + ws[2] + ws[3];
}

// pass 2 (fused): each block computes its own prefix over block_sums, then
// finalizes row_ptr, cursor, dinv, and the dinv-prescaled input Xs.
__global__ void scan3_kernel(const int* __restrict__ cnt, int* __restrict__ row_ptr,
                             int* __restrict__ cursor, float* __restrict__ dinv,
                             const int* __restrict__ block_sums,
                             const float* __restrict__ x, float* __restrict__ Xs, int n) {
    int tid = threadIdx.x, lane = tid & 63;
    int bid = blockIdx.x;
    __shared__ int soff_s;
    __shared__ float sDinv[256];
    if (tid < 64) {
        int sum = 0;
        for (int i = lane; i < bid; i += 64) sum += block_sums[i];
        #pragma unroll
        for (int d = 1; d < 64; d <<= 1) sum += __shfl_xor(sum, d, 64);
        if (lane == 0) soff_s = sum;
    }
    __syncthreads();
    int soff = soff_s;
    int i = bid * 256 + tid;
    float dv = 0.f;
    if (i < n) {
        int r = row_ptr[i] + soff;
        row_ptr[i] = r;
        cursor[i] = r;
        dv = rsqrtf((float)cnt[i] + 1.0f);
        dinv[i] = dv;
    }
    sDinv[tid] = dv;
    if (bid == NB - 1 && tid == 0) row_ptr[n] = soff + block_sums[bid];
    __syncthreads();
    // prescale rows [bid*256, bid*256+256): Xs = x * dinv[row]
    const float4* x4 = (const float4*)x;
    float4* Xs4 = (float4*)Xs;
    for (int t = tid; t < 4096; t += 256) {
        int e4 = bid * 4096 + t;          // global float4 index (16 per row)
        int row = e4 >> 4;
        if (row < n) {
            float4 vv = x4[e4];
            float d = sDinv[row - bid * 256];
            vv.x *= d; vv.y *= d; vv.z *= d; vv.w *= d;
            Xs4[e4] = vv;
        }
    }
}

// 4 edges per thread via int4
__global__ void fill_kernel(const int* __restrict__ src, const int* __restrict__ dst,
                            int* __restrict__ cursor, int* __restrict__ csr_src, int E) {
    int t = blockIdx.x * blockDim.x + threadIdx.x;
    int e = t * 4;
    if (e + 3 < E) {
        int4 d = *(const int4*)&dst[e];
        int4 s = *(const int4*)&src[e];
        int p0 = atomicAdd(&cursor[d.x], 1);
        int p1 = atomicAdd(&cursor[d.y], 1);
        int p2 = atomicAdd(&cursor[d.z], 1);
        int p3 = atomicAdd(&cursor[d.w], 1);
        csr_src[p0] = s.x; csr_src[p1] = s.y;
        csr_src[p2] = s.z; csr_src[p3] = s.w;
    } else {
        for (int k = e; k < E; ++k) {
            int pos = atomicAdd(&cursor[dst[k]], 1);
            csr_src[pos] = src[k];
        }
    }
}

// ---- fused GCN layer -----------------------------------------------------
// Input Xs is pre-scaled (= h * dinv). Per node d:
//   agg = sum_{s in N(d)} Xs[s] + Xs[d]
//   v   = dinv[d] * (agg @ W) + b;  out = relu?(v) * (scale_out ? dinv[d] : 1)
// One wave per node. W^T staged in LDS with XOR-swizzled float4 chunks:
// logical chunk c of row j lives at physical chunk c^(j&15) -> per-phase
// 2-way banks on ds_read_b128 (free).
__global__ void __launch_bounds__(256) layer_kernel(
        const float* __restrict__ Xs, const int* __restrict__ row_ptr,
        const int* __restrict__ csr_src, const float* __restrict__ dinv,
        const float* __restrict__ W, const float* __restrict__ bias,
        float* __restrict__ out, int n, int do_relu, int scale_out) {
    __shared__ __align__(16) float sWt[64 * 64];  // row j: 16 swizzled chunks
    for (int i = threadIdx.x; i < 4096; i += 256) {
        int k = i >> 6, j = i & 63;           // W[k][j]
        int c = k >> 2, r = k & 3;
        sWt[j * 64 + ((c ^ (j & 15)) * 4 + r)] = W[i];
    }

    int wv_ = threadIdx.x >> 6, lane = threadIdx.x & 63;
    int grp = lane >> 4, sub = lane & 15;
    int node = blockIdx.x * 4 + wv_;
    const float4* X4 = (const float4*)Xs;

    float4 acc = make_float4(0.f, 0.f, 0.f, 0.f);
    if (node < n) {
        int s0 = row_ptr[node], s1 = row_ptr[node + 1];
        for (int base = s0; base < s1; base += 64) {
            int m = s1 - base; if (m > 64) m = 64;
            int ld = (lane < m) ? lane : (m - 1);
            int idx = csr_src[base + ld];
            for (int e0 = grp; e0 < m; e0 += 16) {
                int e1 = e0 + 4, e2 = e0 + 8, e3 = e0 + 12;
                int i0 = __shfl(idx, e0, 64);
                int i1 = __shfl(idx, (e1 < m) ? e1 : e0, 64);
                int i2 = __shfl(idx, (e2 < m) ? e2 : e0, 64);
                int i3 = __shfl(idx, (e3 < m) ? e3 : e0, 64);
                float w1 = (e1 < m) ? 1.f : 0.f;
                float w2 = (e2 < m) ? 1.f : 0.f;
                float w3 = (e3 < m) ? 1.f : 0.f;
                float4 v0 = X4[(unsigned)(i0 * 16 + sub)];
                float4 v1 = X4[(unsigned)(i1 * 16 + sub)];
                float4 v2 = X4[(unsigned)(i2 * 16 + sub)];
                float4 v3 = X4[(unsigned)(i3 * 16 + sub)];
                acc.x += v0.x; acc.y += v0.y; acc.z += v0.z; acc.w += v0.w;
                acc.x = fmaf(w1, v1.x, acc.x); acc.y = fmaf(w1, v1.y, acc.y);
                acc.z = fmaf(w1, v1.z, acc.z); acc.w = fmaf(w1, v1.w, acc.w);
                acc.x = fmaf(w2, v2.x, acc.x); acc.y = fmaf(w2, v2.y, acc.y);
                acc.z = fmaf(w2, v2.z, acc.z); acc.w = fmaf(w2, v2.w, acc.w);
                acc.x = fmaf(w3, v3.x, acc.x); acc.y = fmaf(w3, v3.y, acc.y);
                acc.z = fmaf(w3, v3.z, acc.z); acc.w = fmaf(w3, v3.w, acc.w);
            }
        }
    }
    __syncthreads();   // sWt ready; all threads reach this

    // reduce the 4 edge-groups (every lane ends with agg[4*sub .. 4*sub+3])
    acc.x += __shfl_xor(acc.x, 16, 64); acc.y += __shfl_xor(acc.y, 16, 64);
    acc.z += __shfl_xor(acc.z, 16, 64); acc.w += __shfl_xor(acc.w, 16, 64);
    acc.x += __shfl_xor(acc.x, 32, 64); acc.y += __shfl_xor(acc.y, 32, 64);
    acc.z += __shfl_xor(acc.z, 32, 64); acc.w += __shfl_xor(acc.w, 32, 64);

    if (node >= n) return;

    // self-loop term (already dinv-scaled)
    float4 sv = X4[(unsigned)(node * 16 + sub)];
    acc.x += sv.x; acc.y += sv.y; acc.z += sv.z; acc.w += sv.w;

    // matvec: out_j = sum_c sum_{r<4} agg[4c+r] * W[4c+r][j]
    float o = 0.f;
    #pragma unroll
    for (int c = 0; c < 16; ++c) {
        float4 wvv = *(const float4*)&sWt[lane * 64 + ((c ^ (lane & 15)) * 4)];
        float a0 = __int_as_float(__builtin_amdgcn_readlane(__float_as_int(acc.x), c));
        float a1 = __int_as_float(__builtin_amdgcn_readlane(__float_as_int(acc.y), c));
        float a2 = __int_as_float(__builtin_amdgcn_readlane(__float_as_int(acc.z), c));
        float a3 = __int_as_float(__builtin_amdgcn_readlane(__float_as_int(acc.w), c));
        o = fmaf(a0, wvv.x, o); o = fmaf(a1, wvv.y, o);
        o = fmaf(a2, wvv.z, o); o = fmaf(a3, wvv.w, o);
    }
    float di = dinv[node];
    float v = o * di + bias[lane];
    if (do_relu) v = fmaxf(v, 0.f);
    if (scale_out) v *= di;
    out[(unsigned)(node * 64 + lane)] = v;
}

// ---- pooling / classifier ------------------------------------------------

__global__ void pool1_kernel(const float* __restrict__ H, const int* __restrict__ batch,
                             float* __restrict__ partial, int n) {
    int g = blockIdx.x >> 4, sl = blockIdx.x & (NSLICE - 1);
    int lo = 0, hi = n;
    while (lo < hi) { int m = (lo + hi) >> 1; if (batch[m] < g) lo = m + 1; else hi = m; }
    int start = lo;
    lo = start; hi = n;
    while (lo < hi) { int m = (lo + hi) >> 1; if (batch[m] < g + 1) lo = m + 1; else hi = m; }
    int end = lo;
    int len = end - start;
    int ss = start + (int)((long long)len * sl / NSLICE);
    int se = start + (int)((long long)len * (sl + 1) / NSLICE);

    int f = threadIdx.x & 63, c = threadIdx.x >> 6;
    float s = 0.f, m = -INFINITY;
    for (int i = ss + c; i < se; i += 4) {
        float v = H[i * NF + f];
        s += v; m = fmaxf(m, v);
    }
    __shared__ float ssh[4][64], smh[4][64];
    ssh[c][f] = s; smh[c][f] = m;
    __syncthreads();
    if (c == 0) {
        float sum = ssh[0][f] + ssh[1][f] + ssh[2][f] + ssh[3][f];
        float mx = fmaxf(fmaxf(smh[0][f], smh[1][f]), fmaxf(smh[2][f], smh[3][f]));
        partial[(size_t)blockIdx.x * 128 + f] = sum;
        partial[(size_t)blockIdx.x * 128 + 64 + f] = mx;
    }
}

__global__ void pool2_kernel(const float* __restrict__ partial, const int* __restrict__ batch,
                             const float* __restrict__ Wlin, const float* __restrict__ blin,
                             float* __restrict__ out, int n) {
    int g = blockIdx.x;
    int t = threadIdx.x;  // 128
    __shared__ float pooled[128];
    if (t < 64) {
        float sum = 0.f;
        for (int sl = 0; sl < NSLICE; ++sl) sum += partial[((size_t)g * NSLICE + sl) * 128 + t];
        int lo = 0, hi = n;
        while (lo < hi) { int m = (lo + hi) >> 1; if (batch[m] < g) lo = m + 1; else hi = m; }
        int start = lo;
        lo = start; hi = n;
        while (lo < hi) { int m = (lo + hi) >> 1; if (batch[m] < g + 1) lo = m + 1; else hi = m; }
        int cnt = lo - start;
        pooled[t] = sum / fmaxf((float)cnt, 1.0f);
    } else {
        int f = t - 64;
        float mx = -INFINITY;
        for (int sl = 0; sl < NSLICE; ++sl)
            mx = fmaxf(mx, partial[((size_t)g * NSLICE + sl) * 128 + 64 + f]);
        pooled[t] = mx;
    }
    __syncthreads();
    if (t < NC) {
        float acc = blin[t];
        #pragma unroll 8
        for (int k = 0; k < 128; ++k) acc = fmaf(pooled[k], Wlin[k * NC + t], acc);
        out[g * NC + t] = acc;
    }
}

// ---- launch ---------------------------------------------------------------

extern "C" void kernel_launch(void* const* d_in, const int* in_sizes, int n_in,
                              void* d_out, int out_size, void* d_ws, size_t ws_size,
                              hipStream_t stream) {
    const float* x     = (const float*)d_in[0];
    const int*   ei    = (const int*)d_in[1];
    const int*   batch = (const int*)d_in[2];
    const float* W1    = (const float*)d_in[3];
    const float* b1    = (const float*)d_in[4];
    const float* W2    = (const float*)d_in[5];
    const float* b2    = (const float*)d_in[6];
    const float* W3    = (const float*)d_in[7];
    const float* b3    = (const float*)d_in[8];
    const float* Wlin  = (const float*)d_in[9];
    const float* blin  = (const float*)d_in[10];
    const int* src = ei;
    const int* dst = ei + NE;
    float* out = (float*)d_out;

    // workspace layout
    int*   cnt        = (int*)d_ws;                 // 50000
    int*   row_ptr    = cnt + NN;                   // 50001
    int*   cursor     = row_ptr + NN + 1;           // 50000
    int*   block_sums = cursor + NN;                // 197 (pad to 256)
    int*   csr_src    = block_sums + 256;           // 800000
    float* dinv       = (float*)(csr_src + NE);     // 50000
    float* bufA       = dinv + NN;                  // 3.2M  (16B-aligned: offsets all x4)
    float* bufB       = bufA + (size_t)NN * NF;     // 3.2M
    float* partial    = bufB + (size_t)NN * NF;     // 131072

    // CSR build + dinv + prescale
    hipMemsetAsync(cnt, 0, NN * sizeof(int), stream);
    count_kernel<<<(NE / 4 + 255) / 256, 256, 0, stream>>>(dst, cnt, NE);
    scan1_kernel<<<NB, 256, 0, stream>>>(cnt, row_ptr, block_sums, NN);
    scan3_kernel<<<NB, 256, 0, stream>>>(cnt, row_ptr, cursor, dinv, block_sums, x, bufA, NN);
    fill_kernel<<<(NE / 4 + 255) / 256, 256, 0, stream>>>(src, dst, cursor, csr_src, NE);

    // 3 fused GCN layers
    layer_kernel<<<(NN + 3) / 4, 256, 0, stream>>>(bufA, row_ptr, csr_src, dinv, W1, b1,
                                                   bufB, NN, 1, 1);
    layer_kernel<<<(NN + 3) / 4, 256, 0, stream>>>(bufB, row_ptr, csr_src, dinv, W2, b2,
                                                   bufA, NN, 1, 1);
    layer_kernel<<<(NN + 3) / 4, 256, 0, stream>>>(bufA, row_ptr, csr_src, dinv, W3, b3,
                                                   bufB, NN, 0, 0);

    // two-stage pool + fused classifier
    pool1_kernel<<<NG * NSLICE, 256, 0, stream>>>(bufB, batch, partial, NN);
    pool2_kernel<<<NG, 128, 0, stream>>>(partial, batch, Wlin, blin, out, NN);
}

// Round 7
// 190.484 us; speedup vs baseline: 4.0540x; 1.2403x over previous
//
#include <hip/hip_runtime.h>

#define NN 50000
#define NE 800000
#define NF 64
#define NG 64
#define NC 16
#define NSLICE 16
#define NBKT 196   // buckets of 256 nodes: ceil(NN/256)
#define CH 4096    // edges per scatter block
#define SCAP 6144  // per-bucket LDS stage capacity (mean 4096, sigma~64)

// ---- CSR build: two-level bucket counting sort ---------------------------

// P1a: per-bucket histogram (LDS-staged)
__global__ void bhist_kernel(const int* __restrict__ dst, int* __restrict__ bhist, int E) {
    __shared__ int lh[NBKT];
    for (int i = threadIdx.x; i < NBKT; i += 256) lh[i] = 0;
    __syncthreads();
    int e = (blockIdx.x * 256 + threadIdx.x) * 4;
    if (e + 3 < E) {
        int4 d = *(const int4*)&dst[e];
        atomicAdd(&lh[d.x >> 8], 1); atomicAdd(&lh[d.y >> 8], 1);
        atomicAdd(&lh[d.z >> 8], 1); atomicAdd(&lh[d.w >> 8], 1);
    } else {
        for (int k = e; k < E; ++k) atomicAdd(&lh[dst[k] >> 8], 1);
    }
    __syncthreads();
    for (int i = threadIdx.x; i < NBKT; i += 256) if (lh[i]) atomicAdd(&bhist[i], lh[i]);
}

// P1b: scan bucket hist -> bucket_base (+total), init bucket cursors
__global__ void bscan_kernel(const int* __restrict__ bhist, int* __restrict__ bbase,
                             int* __restrict__ bcur) {
    int tid = threadIdx.x, lane = tid & 63, wid = tid >> 6;
    int v = (tid < NBKT) ? bhist[tid] : 0;
    int s = v;
    #pragma unroll
    for (int d = 1; d < 64; d <<= 1) { int t = __shfl_up(s, d, 64); if (lane >= d) s += t; }
    __shared__ int ws[4];
    if (lane == 63) ws[wid] = s;
    __syncthreads();
    int woff = 0;
    for (int k = 0; k < wid; ++k) woff += ws[k];
    int excl = woff + s - v;
    if (tid < NBKT) { bbase[tid] = excl; bcur[tid] = excl; }
    if (tid == NBKT) bbase[NBKT] = excl;
}

// P1c: scatter edges into bucket regions of `pairs`, LDS-staged so global
// writes are contiguous bursts per bucket.
__global__ void __launch_bounds__(256) bscatter_kernel(
        const int* __restrict__ src, const int* __restrict__ dst,
        int* __restrict__ bcur, int2* __restrict__ pairs, int E) {
    __shared__ int lhist[NBKT];
    __shared__ int lbase[NBKT];
    __shared__ int gbase[NBKT];
    __shared__ int2 stage[CH];
    __shared__ short bktOf[CH];
    __shared__ int ws[4];
    int tid = threadIdx.x, lane = tid & 63, wid = tid >> 6;
    for (int i = tid; i < NBKT; i += 256) lhist[i] = 0;
    __syncthreads();
    int e0 = blockIdx.x * CH;
    int m = E - e0; if (m > CH) m = CH;
    int es[16], ed[16], er[16];
    #pragma unroll
    for (int k = 0; k < 16; ++k) {
        int i = tid + k * 256;
        if (i < m) {
            es[k] = src[e0 + i];
            ed[k] = dst[e0 + i];
            er[k] = atomicAdd(&lhist[ed[k] >> 8], 1);
        }
    }
    __syncthreads();
    // block scan of lhist + reserve global space per bucket
    {
        int v = (tid < NBKT) ? lhist[tid] : 0;
        int s = v;
        #pragma unroll
        for (int d = 1; d < 64; d <<= 1) { int t = __shfl_up(s, d, 64); if (lane >= d) s += t; }
        if (lane == 63) ws[wid] = s;
        __syncthreads();
        int woff = 0;
        for (int k = 0; k < wid; ++k) woff += ws[k];
        if (tid < NBKT) {
            lbase[tid] = woff + s - v;
            gbase[tid] = v ? atomicAdd(&bcur[tid], v) : 0;
        }
    }
    __syncthreads();
    #pragma unroll
    for (int k = 0; k < 16; ++k) {
        int i = tid + k * 256;
        if (i < m) {
            int b = ed[k] >> 8;
            int pos = lbase[b] + er[k];
            stage[pos] = make_int2(es[k], ed[k]);
            bktOf[pos] = (short)b;
        }
    }
    __syncthreads();
    for (int i = tid; i < m; i += 256) {
        int b = bktOf[i];
        pairs[gbase[b] + (i - lbase[b])] = stage[i];
    }
}

// P2: per-bucket counting sort by dst -> csr_src (coalesced), row_ptr, dinv,
// fused prescale Xs = x * dinv for this bucket's node range.
__global__ void __launch_bounds__(256) bsort_kernel(
        const int2* __restrict__ pairs, const int* __restrict__ bbase,
        int* __restrict__ csr_src, int* __restrict__ row_ptr, float* __restrict__ dinv,
        const float* __restrict__ x, float* __restrict__ Xs, int n) {
    __shared__ int lh[256];
    __shared__ int lcur[256];
    __shared__ float sdv[256];
    __shared__ int ws[4];
    __shared__ int ssrc[SCAP];
    int tid = threadIdx.x, lane = tid & 63, wid = tid >> 6;
    int b = blockIdx.x;
    int n0 = b << 8;
    int nodes = n - n0; if (nodes > 256) nodes = 256;
    int g0 = bbase[b], cnt = bbase[b + 1] - g0;
    lh[tid] = 0;
    __syncthreads();
    for (int i = tid; i < cnt; i += 256) atomicAdd(&lh[pairs[g0 + i].y - n0], 1);
    __syncthreads();
    int v = lh[tid];
    int s = v;
    #pragma unroll
    for (int d = 1; d < 64; d <<= 1) { int t = __shfl_up(s, d, 64); if (lane >= d) s += t; }
    if (lane == 63) ws[wid] = s;
    __syncthreads();
    int woff = 0;
    for (int k = 0; k < wid; ++k) woff += ws[k];
    int excl = woff + s - v;
    lcur[tid] = excl;
    float dv = rsqrtf((float)v + 1.0f);
    sdv[tid] = dv;
    if (tid < nodes) {
        row_ptr[n0 + tid] = g0 + excl;
        dinv[n0 + tid] = dv;
    }
    if (b == NBKT - 1 && tid == 0) row_ptr[n] = bbase[NBKT];
    __syncthreads();
    if (cnt <= SCAP) {
        for (int i = tid; i < cnt; i += 256) {
            int2 p = pairs[g0 + i];
            int pos = atomicAdd(&lcur[p.y - n0], 1);
            ssrc[pos] = p.x;
        }
        __syncthreads();
        for (int i = tid; i < cnt; i += 256) csr_src[g0 + i] = ssrc[i];
    } else {  // overflow fallback (statistically unreachable)
        for (int i = tid; i < cnt; i += 256) {
            int2 p = pairs[g0 + i];
            int pos = atomicAdd(&lcur[p.y - n0], 1);
            csr_src[g0 + pos] = p.x;
        }
    }
    // fused prescale for this node range
    const float4* x4 = (const float4*)x;
    float4* Xs4 = (float4*)Xs;
    int t0 = n0 << 4;
    int tcnt = nodes << 4;
    for (int t = tid; t < tcnt; t += 256) {
        float4 vv = x4[t0 + t];
        float d = sdv[t >> 4];
        vv.x *= d; vv.y *= d; vv.z *= d; vv.w *= d;
        Xs4[t0 + t] = vv;
    }
}

// ---- fused GCN layer (unchanged from R5) ----------------------------------
__global__ void __launch_bounds__(256) layer_kernel(
        const float* __restrict__ Xs, const int* __restrict__ row_ptr,
        const int* __restrict__ csr_src, const float* __restrict__ dinv,
        const float* __restrict__ W, const float* __restrict__ bias,
        float* __restrict__ out, int n, int do_relu, int scale_out) {
    __shared__ __align__(16) float sWt[64 * 64];  // row j: 16 swizzled chunks
    for (int i = threadIdx.x; i < 4096; i += 256) {
        int k = i >> 6, j = i & 63;           // W[k][j]
        int c = k >> 2, r = k & 3;
        sWt[j * 64 + ((c ^ (j & 15)) * 4 + r)] = W[i];
    }

    int wv_ = threadIdx.x >> 6, lane = threadIdx.x & 63;
    int grp = lane >> 4, sub = lane & 15;
    int node = blockIdx.x * 4 + wv_;
    const float4* X4 = (const float4*)Xs;

    float4 acc = make_float4(0.f, 0.f, 0.f, 0.f);
    if (node < n) {
        int s0 = row_ptr[node], s1 = row_ptr[node + 1];
        for (int base = s0; base < s1; base += 64) {
            int m = s1 - base; if (m > 64) m = 64;
            int ld = (lane < m) ? lane : (m - 1);
            int idx = csr_src[base + ld];
            for (int e0 = grp; e0 < m; e0 += 16) {
                int e1 = e0 + 4, e2 = e0 + 8, e3 = e0 + 12;
                int i0 = __shfl(idx, e0, 64);
                int i1 = __shfl(idx, (e1 < m) ? e1 : e0, 64);
                int i2 = __shfl(idx, (e2 < m) ? e2 : e0, 64);
                int i3 = __shfl(idx, (e3 < m) ? e3 : e0, 64);
                float w1 = (e1 < m) ? 1.f : 0.f;
                float w2 = (e2 < m) ? 1.f : 0.f;
                float w3 = (e3 < m) ? 1.f : 0.f;
                float4 v0 = X4[(unsigned)(i0 * 16 + sub)];
                float4 v1 = X4[(unsigned)(i1 * 16 + sub)];
                float4 v2 = X4[(unsigned)(i2 * 16 + sub)];
                float4 v3 = X4[(unsigned)(i3 * 16 + sub)];
                acc.x += v0.x; acc.y += v0.y; acc.z += v0.z; acc.w += v0.w;
                acc.x = fmaf(w1, v1.x, acc.x); acc.y = fmaf(w1, v1.y, acc.y);
                acc.z = fmaf(w1, v1.z, acc.z); acc.w = fmaf(w1, v1.w, acc.w);
                acc.x = fmaf(w2, v2.x, acc.x); acc.y = fmaf(w2, v2.y, acc.y);
                acc.z = fmaf(w2, v2.z, acc.z); acc.w = fmaf(w2, v2.w, acc.w);
                acc.x = fmaf(w3, v3.x, acc.x); acc.y = fmaf(w3, v3.y, acc.y);
                acc.z = fmaf(w3, v3.z, acc.z); acc.w = fmaf(w3, v3.w, acc.w);
            }
        }
    }
    __syncthreads();

    acc.x += __shfl_xor(acc.x, 16, 64); acc.y += __shfl_xor(acc.y, 16, 64);
    acc.z += __shfl_xor(acc.z, 16, 64); acc.w += __shfl_xor(acc.w, 16, 64);
    acc.x += __shfl_xor(acc.x, 32, 64); acc.y += __shfl_xor(acc.y, 32, 64);
    acc.z += __shfl_xor(acc.z, 32, 64); acc.w += __shfl_xor(acc.w, 32, 64);

    if (node >= n) return;

    float4 sv = X4[(unsigned)(node * 16 + sub)];
    acc.x += sv.x; acc.y += sv.y; acc.z += sv.z; acc.w += sv.w;

    float o = 0.f;
    #pragma unroll
    for (int c = 0; c < 16; ++c) {
        float4 wvv = *(const float4*)&sWt[lane * 64 + ((c ^ (lane & 15)) * 4)];
        float a0 = __int_as_float(__builtin_amdgcn_readlane(__float_as_int(acc.x), c));
        float a1 = __int_as_float(__builtin_amdgcn_readlane(__float_as_int(acc.y), c));
        float a2 = __int_as_float(__builtin_amdgcn_readlane(__float_as_int(acc.z), c));
        float a3 = __int_as_float(__builtin_amdgcn_readlane(__float_as_int(acc.w), c));
        o = fmaf(a0, wvv.x, o); o = fmaf(a1, wvv.y, o);
        o = fmaf(a2, wvv.z, o); o = fmaf(a3, wvv.w, o);
    }
    float di = dinv[node];
    float vv = o * di + bias[lane];
    if (do_relu) vv = fmaxf(vv, 0.f);
    if (scale_out) vv *= di;
    out[(unsigned)(node * 64 + lane)] = vv;
}

// ---- pooling / classifier ------------------------------------------------

__global__ void pool1_kernel(const float* __restrict__ H, const int* __restrict__ batch,
                             float* __restrict__ partial, int n) {
    int g = blockIdx.x >> 4, sl = blockIdx.x & (NSLICE - 1);
    int lo = 0, hi = n;
    while (lo < hi) { int m = (lo + hi) >> 1; if (batch[m] < g) lo = m + 1; else hi = m; }
    int start = lo;
    lo = start; hi = n;
    while (lo < hi) { int m = (lo + hi) >> 1; if (batch[m] < g + 1) lo = m + 1; else hi = m; }
    int end = lo;
    int len = end - start;
    int ss = start + (int)((long long)len * sl / NSLICE);
    int se = start + (int)((long long)len * (sl + 1) / NSLICE);

    int f = threadIdx.x & 63, c = threadIdx.x >> 6;
    float s = 0.f, m = -INFINITY;
    for (int i = ss + c; i < se; i += 4) {
        float v = H[i * NF + f];
        s += v; m = fmaxf(m, v);
    }
    __shared__ float ssh[4][64], smh[4][64];
    ssh[c][f] = s; smh[c][f] = m;
    __syncthreads();
    if (c == 0) {
        float sum = ssh[0][f] + ssh[1][f] + ssh[2][f] + ssh[3][f];
        float mx = fmaxf(fmaxf(smh[0][f], smh[1][f]), fmaxf(smh[2][f], smh[3][f]));
        partial[(size_t)blockIdx.x * 128 + f] = sum;
        partial[(size_t)blockIdx.x * 128 + 64 + f] = mx;
    }
}

__global__ void pool2_kernel(const float* __restrict__ partial, const int* __restrict__ batch,
                             const float* __restrict__ Wlin, const float* __restrict__ blin,
                             float* __restrict__ out, int n) {
    int g = blockIdx.x;
    int t = threadIdx.x;  // 128
    __shared__ float pooled[128];
    if (t < 64) {
        float sum = 0.f;
        for (int sl = 0; sl < NSLICE; ++sl) sum += partial[((size_t)g * NSLICE + sl) * 128 + t];
        int lo = 0, hi = n;
        while (lo < hi) { int m = (lo + hi) >> 1; if (batch[m] < g) lo = m + 1; else hi = m; }
        int start = lo;
        lo = start; hi = n;
        while (lo < hi) { int m = (lo + hi) >> 1; if (batch[m] < g + 1) lo = m + 1; else hi = m; }
        int cnt = lo - start;
        pooled[t] = sum / fmaxf((float)cnt, 1.0f);
    } else {
        int f = t - 64;
        float mx = -INFINITY;
        for (int sl = 0; sl < NSLICE; ++sl)
            mx = fmaxf(mx, partial[((size_t)g * NSLICE + sl) * 128 + 64 + f]);
        pooled[t] = mx;
    }
    __syncthreads();
    if (t < NC) {
        float acc = blin[t];
        #pragma unroll 8
        for (int k = 0; k < 128; ++k) acc = fmaf(pooled[k], Wlin[k * NC + t], acc);
        out[g * NC + t] = acc;
    }
}

// ---- launch ---------------------------------------------------------------

extern "C" void kernel_launch(void* const* d_in, const int* in_sizes, int n_in,
                              void* d_out, int out_size, void* d_ws, size_t ws_size,
                              hipStream_t stream) {
    const float* x     = (const float*)d_in[0];
    const int*   ei    = (const int*)d_in[1];
    const int*   batch = (const int*)d_in[2];
    const float* W1    = (const float*)d_in[3];
    const float* b1    = (const float*)d_in[4];
    const float* W2    = (const float*)d_in[5];
    const float* b2    = (const float*)d_in[6];
    const float* W3    = (const float*)d_in[7];
    const float* b3    = (const float*)d_in[8];
    const float* Wlin  = (const float*)d_in[9];
    const float* blin  = (const float*)d_in[10];
    const int* src = ei;
    const int* dst = ei + NE;
    float* out = (float*)d_out;

    // workspace layout (all offsets keep 16B alignment)
    int*   bhist   = (int*)d_ws;                    // 256
    int*   bbase   = bhist + 256;                   // 256 (uses NBKT+1)
    int*   bcur    = bbase + 256;                   // 256
    int*   row_ptr = bcur + 256;                    // 50008
    int*   csr_src = row_ptr + 50008;               // 800000
    float* dinv    = (float*)(csr_src + NE);        // 50008
    float* bufA    = dinv + 50008;                  // 3.2M
    float* bufB    = bufA + (size_t)NN * NF;        // 3.2M (aliased as pairs in build)
    float* partial = bufB + (size_t)NN * NF;        // 131072
    int2*  pairs   = (int2*)bufB;                   // 6.4MB <= bufB, used only pre-layer

    // CSR build (bucket counting sort) + dinv + prescale
    hipMemsetAsync(bhist, 0, 256 * sizeof(int), stream);
    bhist_kernel<<<(NE / 4 + 255) / 256, 256, 0, stream>>>(dst, bhist, NE);
    bscan_kernel<<<1, 256, 0, stream>>>(bhist, bbase, bcur);
    bscatter_kernel<<<(NE + CH - 1) / CH, 256, 0, stream>>>(src, dst, bcur, pairs, NE);
    bsort_kernel<<<NBKT, 256, 0, stream>>>(pairs, bbase, csr_src, row_ptr, dinv, x, bufA, NN);

    // 3 fused GCN layers
    layer_kernel<<<(NN + 3) / 4, 256, 0, stream>>>(bufA, row_ptr, csr_src, dinv, W1, b1,
                                                   bufB, NN, 1, 1);
    layer_kernel<<<(NN + 3) / 4, 256, 0, stream>>>(bufB, row_ptr, csr_src, dinv, W2, b2,
                                                   bufA, NN, 1, 1);
    layer_kernel<<<(NN + 3) / 4, 256, 0, stream>>>(bufA, row_ptr, csr_src, dinv, W3, b3,
                                                   bufB, NN, 0, 0);

    // two-stage pool + fused classifier
    pool1_kernel<<<NG * NSLICE, 256, 0, stream>>>(bufB, batch, partial, NN);
    pool2_kernel<<<NG, 128, 0, stream>>>(partial, batch, Wlin, blin, out, NN);
}